// Round 14
// baseline (393.749 us; speedup 1.0000x reference)
//
#include <hip/hip_runtime.h>
#include <hip/hip_bf16.h>
#include <hip/hip_fp16.h>

#define NN 50000
#define NE 1600000
#define DIM 128
#define NU 10000
#define NB 256           // histogram/scatter chunks
#define SLICE_W 12500    // NN/4 packed-uint8 words per slice
#define NE4 (NE / 4)
#define CHUNK4 ((NE4 + NB - 1) / NB)   // int4 per block
#define NSC 49           // scan blocks: ceil(NN/1024)

// Fused per-chunk packed-uint8 histograms: blocks [0,NB) -> dst, [NB,2NB) -> src
__global__ __launch_bounds__(512) void k_hist(const int4* __restrict__ src4,
                                              const int4* __restrict__ dst4,
                                              unsigned int* __restrict__ histD,
                                              unsigned int* __restrict__ histS) {
    __shared__ unsigned int lh[SLICE_W];   // 50 KB
    for (int i = threadIdx.x; i < SLICE_W; i += 512) lh[i] = 0u;
    __syncthreads();
    int b = blockIdx.x & (NB - 1);
    const int4* idx4 = (blockIdx.x < NB) ? dst4 : src4;
    unsigned int* out = ((blockIdx.x < NB) ? histD : histS) + (size_t)b * SLICE_W;
    int beg = b * CHUNK4, end = min(beg + CHUNK4, NE4);
    for (int i = beg + threadIdx.x; i < end; i += 512) {
        int4 v = idx4[i];
        atomicAdd(&lh[v.x >> 2], 1u << ((v.x & 3) * 8));
        atomicAdd(&lh[v.y >> 2], 1u << ((v.y & 3) * 8));
        atomicAdd(&lh[v.z >> 2], 1u << ((v.z & 3) * 8));
        atomicAdd(&lh[v.w >> 2], 1u << ((v.w & 3) * 8));
    }
    __syncthreads();
    for (int i = threadIdx.x; i < SLICE_W; i += 512) out[i] = lh[i];
}

// Sum NB slices per node; emit din, cs, cd, per-block degree partials
__global__ __launch_bounds__(256) void k_reduce_norms(const unsigned int* __restrict__ histD,
                                                      const unsigned int* __restrict__ histS,
                                                      int* __restrict__ din,
                                                      float* __restrict__ cs, float* __restrict__ cd,
                                                      int* __restrict__ partials) {
    __shared__ int red[256];
    int wi = blockIdx.x * blockDim.x + threadIdx.x;
    unsigned int d0 = 0, d1 = 0, d2 = 0, d3 = 0, s0 = 0, s1 = 0, s2 = 0, s3 = 0;
    if (wi < SLICE_W) {
        for (int b = 0; b < NB; ++b) {
            unsigned int wd = histD[(size_t)b * SLICE_W + wi];
            unsigned int ws = histS[(size_t)b * SLICE_W + wi];
            d0 += wd & 0xFFu; d1 += (wd >> 8) & 0xFFu; d2 += (wd >> 16) & 0xFFu; d3 += wd >> 24;
            s0 += ws & 0xFFu; s1 += (ws >> 8) & 0xFFu; s2 += (ws >> 16) & 0xFFu; s3 += ws >> 24;
        }
        int n = wi * 4;
        *(int4*)&din[n] = make_int4(d0, d1, d2, d3);
        float4 vcd, vcs;
        vcd.x = rsqrtf(fmaxf((float)d0, 1.f)); vcd.y = rsqrtf(fmaxf((float)d1, 1.f));
        vcd.z = rsqrtf(fmaxf((float)d2, 1.f)); vcd.w = rsqrtf(fmaxf((float)d3, 1.f));
        vcs.x = rsqrtf(fmaxf((float)s0, 1.f)); vcs.y = rsqrtf(fmaxf((float)s1, 1.f));
        vcs.z = rsqrtf(fmaxf((float)s2, 1.f)); vcs.w = rsqrtf(fmaxf((float)s3, 1.f));
        *(float4*)&cd[n] = vcd;
        *(float4*)&cs[n] = vcs;
    }
    red[threadIdx.x] = (int)(d0 + d1 + d2 + d3);
    __syncthreads();
    for (int off = 128; off > 0; off >>= 1) {
        if (threadIdx.x < off) red[threadIdx.x] += red[threadIdx.x + off];
        __syncthreads();
    }
    if (threadIdx.x == 0) partials[blockIdx.x] = red[0];
}

__global__ __launch_bounds__(64) void k_scan2(const int* __restrict__ partials,
                                              int* __restrict__ bases) {
    int lane = threadIdx.x;
    int v = (lane < NSC) ? partials[lane] : 0;
    int s = v;
    for (int off = 1; off < 64; off <<= 1) {
        int n = __shfl_up(s, off);
        if (lane >= off) s += n;
    }
    if (lane < NSC) bases[lane] = s - v;
}

__global__ __launch_bounds__(256) void k_scan3(const int* __restrict__ din,
                                               const int* __restrict__ bases,
                                               int* __restrict__ offs) {
    __shared__ int part[256];
    int t = threadIdx.x;
    int n0 = blockIdx.x * 1024 + t * 4;
    int4 d = make_int4(0, 0, 0, 0);
    if (n0 < NN) d = *(const int4*)&din[n0];
    int tsum = d.x + d.y + d.z + d.w;
    part[t] = tsum;
    __syncthreads();
    for (int off = 1; off < 256; off <<= 1) {
        int v = (t >= off) ? part[t - off] : 0;
        __syncthreads();
        part[t] += v;
        __syncthreads();
    }
    if (n0 < NN) {
        int o = bases[blockIdx.x] + part[t] - tsum;
        *(int4*)&offs[n0] = make_int4(o, o + d.x, o + d.x + d.y, o + d.x + d.y + d.z);
    }
}

// rel8[b][n] = sum over b' < b of histD[b'][n]  (<= deg_in, fits uint8)
__global__ __launch_bounds__(256) void k_blockbase(const unsigned int* __restrict__ histD,
                                                   unsigned char* __restrict__ rel8) {
    int n = blockIdx.x * blockDim.x + threadIdx.x;
    if (n >= NN) return;
    int wi = n >> 2, sh = (n & 3) * 8;
    unsigned int run = 0;
    for (int b = 0; b < NB; ++b) {
        rel8[(size_t)b * NN + n] = (unsigned char)run;
        run += (histD[(size_t)b * SLICE_W + wi] >> sh) & 0xFFu;
    }
}

// Atomic-free CSC scatter: local position from LDS packed-byte cursor
__global__ __launch_bounds__(512) void k_scatter2(const int4* __restrict__ src4,
                                                  const int4* __restrict__ dst4,
                                                  const int* __restrict__ offs,
                                                  const unsigned char* __restrict__ rel8,
                                                  int* __restrict__ csc) {
    __shared__ unsigned int lc[SLICE_W];   // 50 KB
    for (int i = threadIdx.x; i < SLICE_W; i += 512) lc[i] = 0u;
    __syncthreads();
    int b = blockIdx.x;
    const unsigned char* rel = rel8 + (size_t)b * NN;
    int beg = b * CHUNK4, end = min(beg + CHUNK4, NE4);
    for (int i = beg + threadIdx.x; i < end; i += 512) {
        int4 s = src4[i];
        int4 d = dst4[i];
#pragma unroll
        for (int j = 0; j < 4; ++j) {
            int dd = (j == 0) ? d.x : (j == 1) ? d.y : (j == 2) ? d.z : d.w;
            int ss = (j == 0) ? s.x : (j == 1) ? s.y : (j == 2) ? s.z : s.w;
            int sh = (dd & 3) * 8;
            unsigned int old = atomicAdd(&lc[dd >> 2], 1u << sh);
            int local = (old >> sh) & 0xFF;
            csc[offs[dd] + rel[dd] + local] = ss;
        }
    }
}

// Y[r][:] = fp16((X[r][:] @ W) * cs[r]) ; W staged fp16 in LDS (40KB total -> 4 blocks/CU)
__global__ __launch_bounds__(256) void k_matmul_cs(const float* __restrict__ X,
                                                   const float* __restrict__ W,
                                                   const float* __restrict__ cs,
                                                   __half* __restrict__ Y, int nrows) {
    __shared__ __half sW[DIM * DIM];  // 32 KB
    __shared__ float sX[16][DIM];     //  8 KB
    for (int i = threadIdx.x * 4; i < DIM * DIM; i += 256 * 4) {
        float4 w4 = *(const float4*)&W[i];
        *(__half2*)&sW[i]     = __float22half2_rn(make_float2(w4.x, w4.y));
        *(__half2*)&sW[i + 2] = __float22half2_rn(make_float2(w4.z, w4.w));
    }
    int rl = threadIdx.x >> 6;
    int c = (threadIdx.x & 63) * 2;
    int ngroups = (nrows + 15) >> 4;
    for (int g = blockIdx.x; g < ngroups; g += gridDim.x) {
        __syncthreads();
        {
            int row = threadIdx.x >> 4;
            int col = (threadIdx.x & 15) * 8;
            int rr = min(g * 16 + row, nrows - 1);
            const float* xp = X + (size_t)rr * DIM + col;
            *(float4*)&sX[row][col] = *(const float4*)xp;
            *(float4*)&sX[row][col + 4] = *(const float4*)(xp + 4);
        }
        __syncthreads();
        float acc[4][2] = {};
#pragma unroll 4
        for (int k = 0; k < DIM; ++k) {
            float2 w = __half22float2(*(const __half2*)&sW[k * DIM + c]);
            float x0 = sX[rl * 4 + 0][k];
            float x1 = sX[rl * 4 + 1][k];
            float x2 = sX[rl * 4 + 2][k];
            float x3 = sX[rl * 4 + 3][k];
            acc[0][0] = fmaf(x0, w.x, acc[0][0]); acc[0][1] = fmaf(x0, w.y, acc[0][1]);
            acc[1][0] = fmaf(x1, w.x, acc[1][0]); acc[1][1] = fmaf(x1, w.y, acc[1][1]);
            acc[2][0] = fmaf(x2, w.x, acc[2][0]); acc[2][1] = fmaf(x2, w.y, acc[2][1]);
            acc[3][0] = fmaf(x3, w.x, acc[3][0]); acc[3][1] = fmaf(x3, w.y, acc[3][1]);
        }
#pragma unroll
        for (int j = 0; j < 4; ++j) {
            int r = g * 16 + rl * 4 + j;
            if (r < nrows) {
                float s = cs[r];
                __half2 hv = __float22half2_rn(make_float2(acc[j][0] * s, acc[j][1] * s));
                *(__half2*)&Y[(size_t)r * DIM + c] = hv;
            }
        }
    }
}

// XCD-pinned column-chunk aggregate: each XCD (bid&7) owns one 32-dim chunk
// (3.2MB, fits 4MB per-XCD L2). Wave: 8 edge-slots x 8 lanes x 8B (one 64B
// line per gather), 4-deep unroll = 32 gathers in flight.
__global__ __launch_bounds__(256) void k_aggregate(const __half* __restrict__ hs,
                                                   const int* __restrict__ csc,
                                                   const int* __restrict__ offs,
                                                   const int* __restrict__ din,
                                                   const float* __restrict__ cd,
                                                   const float* __restrict__ bias,
                                                   float* __restrict__ out) {
    int bid = blockIdx.x;
    int xcd = bid & 7;
    int chunk = xcd >> 1;                   // dims [chunk*32, chunk*32+32)
    int g = (bid >> 3) * 2 + (bid & 1);     // dst quad [0, 12500)
    int wid = threadIdx.x >> 6;
    int lane = threadIdx.x & 63;
    int slot = lane >> 3;                   // edge slot 0..7
    int l = lane & 7;                       // 8B group: dims chunk*32 + l*4 ..+3
    int d = g * 4 + wid;                    // NN % 4 == 0
    int beg = offs[d];
    int end = beg + din[d];
    const __half* base = hs + chunk * 32 + l * 4;
    float a0 = 0.f, a1 = 0.f, a2 = 0.f, a3 = 0.f;
    float b0 = 0.f, b1 = 0.f, b2 = 0.f, b3 = 0.f;
    float c0 = 0.f, c1 = 0.f, c2 = 0.f, c3 = 0.f;
    float e0 = 0.f, e1 = 0.f, e2 = 0.f, e3 = 0.f;
    int i = beg + slot;
    for (; i + 24 < end; i += 32) {
        int s0 = csc[i], s1 = csc[i + 8], s2 = csc[i + 16], s3 = csc[i + 24];
        short4 v0 = *(const short4*)(base + (size_t)s0 * DIM);
        short4 v1 = *(const short4*)(base + (size_t)s1 * DIM);
        short4 v2 = *(const short4*)(base + (size_t)s2 * DIM);
        short4 v3 = *(const short4*)(base + (size_t)s3 * DIM);
        float2 x0 = __half22float2(*(const __half2*)&v0.x);
        float2 x1 = __half22float2(*(const __half2*)&v0.z);
        float2 y0 = __half22float2(*(const __half2*)&v1.x);
        float2 y1 = __half22float2(*(const __half2*)&v1.z);
        float2 z0 = __half22float2(*(const __half2*)&v2.x);
        float2 z1 = __half22float2(*(const __half2*)&v2.z);
        float2 w0 = __half22float2(*(const __half2*)&v3.x);
        float2 w1 = __half22float2(*(const __half2*)&v3.z);
        a0 += x0.x; a1 += x0.y; a2 += x1.x; a3 += x1.y;
        b0 += y0.x; b1 += y0.y; b2 += y1.x; b3 += y1.y;
        c0 += z0.x; c1 += z0.y; c2 += z1.x; c3 += z1.y;
        e0 += w0.x; e1 += w0.y; e2 += w1.x; e3 += w1.y;
    }
    for (; i < end; i += 8) {
        int s = csc[i];
        short4 v = *(const short4*)(base + (size_t)s * DIM);
        float2 x0 = __half22float2(*(const __half2*)&v.x);
        float2 x1 = __half22float2(*(const __half2*)&v.z);
        a0 += x0.x; a1 += x0.y; a2 += x1.x; a3 += x1.y;
    }
    a0 += b0 + c0 + e0; a1 += b1 + c1 + e1;
    a2 += b2 + c2 + e2; a3 += b3 + c3 + e3;
    // reduce across the 8 slots (lanes with equal l): butterfly over bits 3,4,5
    a0 += __shfl(a0, lane ^ 8);  a1 += __shfl(a1, lane ^ 8);
    a2 += __shfl(a2, lane ^ 8);  a3 += __shfl(a3, lane ^ 8);
    a0 += __shfl(a0, lane ^ 16); a1 += __shfl(a1, lane ^ 16);
    a2 += __shfl(a2, lane ^ 16); a3 += __shfl(a3, lane ^ 16);
    a0 += __shfl(a0, lane ^ 32); a1 += __shfl(a1, lane ^ 32);
    a2 += __shfl(a2, lane ^ 32); a3 += __shfl(a3, lane ^ 32);
    if (slot == 0) {
        float c = cd[d];
        float4 bv = *(const float4*)&bias[chunk * 32 + l * 4];
        float4 o;
        o.x = fmaxf(fmaf(a0, c, bv.x), 0.f);
        o.y = fmaxf(fmaf(a1, c, bv.y), 0.f);
        o.z = fmaxf(fmaf(a2, c, bv.z), 0.f);
        o.w = fmaxf(fmaf(a3, c, bv.w), 0.f);
        *(float4*)&out[(size_t)d * DIM + chunk * 32 + l * 4] = o;
    }
}

// R[u][:] = tanh(h[users[u]] @ Ws1 + bs1) @ Ws2 + bs2
__global__ __launch_bounds__(256) void k_sr_head(const float* __restrict__ h,
                                                 const int* __restrict__ users,
                                                 const float* __restrict__ Ws1,
                                                 const float* __restrict__ bs1,
                                                 const float* __restrict__ Ws2,
                                                 const float* __restrict__ bs2,
                                                 float* __restrict__ R, int nu) {
    __shared__ float sW1[DIM * 64];
    __shared__ float sW2[64 * 64];
    __shared__ float sU[4][DIM];
    __shared__ float sT[4][64];
    for (int i = threadIdx.x * 4; i < DIM * 64; i += 256 * 4)
        *(float4*)&sW1[i] = *(const float4*)&Ws1[i];
    for (int i = threadIdx.x * 4; i < 64 * 64; i += 256 * 4)
        *(float4*)&sW2[i] = *(const float4*)&Ws2[i];
    int ul = threadIdx.x >> 6;
    int c = threadIdx.x & 63;
    for (int base = blockIdx.x * 4; base < nu; base += gridDim.x * 4) {
        int u = base + ul;
        __syncthreads();
        if (u < nu) {
            int node = users[u];
            *(float2*)&sU[ul][c * 2] = *(const float2*)&h[(size_t)node * DIM + c * 2];
        }
        __syncthreads();
        float t = 0.f;
        if (u < nu) {
            float acc = bs1[c];
#pragma unroll 8
            for (int k = 0; k < DIM; ++k) acc = fmaf(sU[ul][k], sW1[k * 64 + c], acc);
            t = tanhf(acc);
        }
        sT[ul][c] = t;
        __syncthreads();
        if (u < nu) {
            float acc = bs2[c];
#pragma unroll 8
            for (int k = 0; k < 64; ++k) acc = fmaf(sT[ul][k], sW2[k * 64 + c], acc);
            R[(size_t)u * 64 + c] = acc;
        }
    }
}

extern "C" void kernel_launch(void* const* d_in, const int* in_sizes, int n_in,
                              void* d_out, int out_size, void* d_ws, size_t ws_size,
                              hipStream_t stream) {
    const float* features = (const float*)d_in[0];
    const float* W0  = (const float*)d_in[1];
    const float* b0  = (const float*)d_in[2];
    const float* W1  = (const float*)d_in[3];
    const float* b1  = (const float*)d_in[4];
    const float* Ws1 = (const float*)d_in[5];
    const float* bs1 = (const float*)d_in[6];
    const float* Ws2 = (const float*)d_in[7];
    const float* bs2 = (const float*)d_in[8];
    const int* src   = (const int*)d_in[9];
    const int* dst   = (const int*)d_in[10];
    const int* users = (const int*)d_in[11];

    float* R = (float*)d_out;
    float* H = (float*)d_out + (size_t)NU * 64;

    char* ws = (char*)d_ws;
    __half* hsA  = (__half*)(ws + 0);                      // 12.8 MB
    unsigned int* histD = (unsigned int*)(ws + 0);         // 12.8 MB (256 x 50000B)
    unsigned int* histS = (unsigned int*)(ws + 12800000);  // 12.8 MB
    unsigned char* rel8 = (unsigned char*)(ws + 12800000); // 12.8 MB (overlays dead histS)
    int* csc     = (int*)(ws + 25600000);                  //  6.4 MB
    int*   din   = (int*)  (ws + 32000000);
    float* cs    = (float*)(ws + 32200000);
    float* cd    = (float*)(ws + 32400000);
    int*   offs  = (int*)  (ws + 32600000);
    int*   partials = (int*)(ws + 32800000);
    int*   bases    = (int*)(ws + 32801024);

    k_hist<<<2 * NB, 512, 0, stream>>>((const int4*)src, (const int4*)dst, histD, histS);
    k_reduce_norms<<<NSC, 256, 0, stream>>>(histD, histS, din, cs, cd, partials);
    k_scan2<<<1, 64, 0, stream>>>(partials, bases);
    k_scan3<<<NSC, 256, 0, stream>>>(din, bases, offs);
    k_blockbase<<<(NN + 255) / 256, 256, 0, stream>>>(histD, rel8);
    k_scatter2<<<NB, 512, 0, stream>>>((const int4*)src, (const int4*)dst, offs, rel8, csc);

    // layer 1
    k_matmul_cs<<<1024, 256, 0, stream>>>(features, W0, cs, hsA, NN);
    k_aggregate<<<50000, 256, 0, stream>>>(hsA, csc, offs, din, cd, b0, H);

    // layer 2
    k_matmul_cs<<<1024, 256, 0, stream>>>(H, W1, cs, hsA, NN);
    k_aggregate<<<50000, 256, 0, stream>>>(hsA, csc, offs, din, cd, b1, H);

    // SR head
    k_sr_head<<<625, 256, 0, stream>>>(H, users, Ws1, bs1, Ws2, bs2, R, NU);
}

// Round 15
// 291.278 us; speedup vs baseline: 1.3518x; 1.3518x over previous
//
#include <hip/hip_runtime.h>
#include <hip/hip_bf16.h>
#include <hip/hip_fp16.h>

#define NN 50000
#define NE 1600000
#define DIM 128
#define NU 10000
#define NB 256           // histogram/scatter chunks
#define SLICE_W 12500    // NN/4 packed-uint8 words per slice
#define NE4 (NE / 4)
#define CHUNK4 ((NE4 + NB - 1) / NB)   // int4 per block
#define NSC 49           // scan blocks: ceil(NN/1024)

// Fused per-chunk packed-uint8 histograms: blocks [0,NB) -> dst, [NB,2NB) -> src
__global__ __launch_bounds__(512) void k_hist(const int4* __restrict__ src4,
                                              const int4* __restrict__ dst4,
                                              unsigned int* __restrict__ histD,
                                              unsigned int* __restrict__ histS) {
    __shared__ unsigned int lh[SLICE_W];   // 50 KB
    for (int i = threadIdx.x; i < SLICE_W; i += 512) lh[i] = 0u;
    __syncthreads();
    int b = blockIdx.x & (NB - 1);
    const int4* idx4 = (blockIdx.x < NB) ? dst4 : src4;
    unsigned int* out = ((blockIdx.x < NB) ? histD : histS) + (size_t)b * SLICE_W;
    int beg = b * CHUNK4, end = min(beg + CHUNK4, NE4);
    for (int i = beg + threadIdx.x; i < end; i += 512) {
        int4 v = idx4[i];
        atomicAdd(&lh[v.x >> 2], 1u << ((v.x & 3) * 8));
        atomicAdd(&lh[v.y >> 2], 1u << ((v.y & 3) * 8));
        atomicAdd(&lh[v.z >> 2], 1u << ((v.z & 3) * 8));
        atomicAdd(&lh[v.w >> 2], 1u << ((v.w & 3) * 8));
    }
    __syncthreads();
    for (int i = threadIdx.x; i < SLICE_W; i += 512) out[i] = lh[i];
}

// Sum NB slices per node; emit din, cs, cd, per-block degree partials
__global__ __launch_bounds__(256) void k_reduce_norms(const unsigned int* __restrict__ histD,
                                                      const unsigned int* __restrict__ histS,
                                                      int* __restrict__ din,
                                                      float* __restrict__ cs, float* __restrict__ cd,
                                                      int* __restrict__ partials) {
    __shared__ int red[256];
    int wi = blockIdx.x * blockDim.x + threadIdx.x;
    unsigned int d0 = 0, d1 = 0, d2 = 0, d3 = 0, s0 = 0, s1 = 0, s2 = 0, s3 = 0;
    if (wi < SLICE_W) {
        for (int b = 0; b < NB; ++b) {
            unsigned int wd = histD[(size_t)b * SLICE_W + wi];
            unsigned int ws = histS[(size_t)b * SLICE_W + wi];
            d0 += wd & 0xFFu; d1 += (wd >> 8) & 0xFFu; d2 += (wd >> 16) & 0xFFu; d3 += wd >> 24;
            s0 += ws & 0xFFu; s1 += (ws >> 8) & 0xFFu; s2 += (ws >> 16) & 0xFFu; s3 += ws >> 24;
        }
        int n = wi * 4;
        *(int4*)&din[n] = make_int4(d0, d1, d2, d3);
        float4 vcd, vcs;
        vcd.x = rsqrtf(fmaxf((float)d0, 1.f)); vcd.y = rsqrtf(fmaxf((float)d1, 1.f));
        vcd.z = rsqrtf(fmaxf((float)d2, 1.f)); vcd.w = rsqrtf(fmaxf((float)d3, 1.f));
        vcs.x = rsqrtf(fmaxf((float)s0, 1.f)); vcs.y = rsqrtf(fmaxf((float)s1, 1.f));
        vcs.z = rsqrtf(fmaxf((float)s2, 1.f)); vcs.w = rsqrtf(fmaxf((float)s3, 1.f));
        *(float4*)&cd[n] = vcd;
        *(float4*)&cs[n] = vcs;
    }
    red[threadIdx.x] = (int)(d0 + d1 + d2 + d3);
    __syncthreads();
    for (int off = 128; off > 0; off >>= 1) {
        if (threadIdx.x < off) red[threadIdx.x] += red[threadIdx.x + off];
        __syncthreads();
    }
    if (threadIdx.x == 0) partials[blockIdx.x] = red[0];
}

__global__ __launch_bounds__(64) void k_scan2(const int* __restrict__ partials,
                                              int* __restrict__ bases) {
    int lane = threadIdx.x;
    int v = (lane < NSC) ? partials[lane] : 0;
    int s = v;
    for (int off = 1; off < 64; off <<= 1) {
        int n = __shfl_up(s, off);
        if (lane >= off) s += n;
    }
    if (lane < NSC) bases[lane] = s - v;
}

__global__ __launch_bounds__(256) void k_scan3(const int* __restrict__ din,
                                               const int* __restrict__ bases,
                                               int* __restrict__ offs) {
    __shared__ int part[256];
    int t = threadIdx.x;
    int n0 = blockIdx.x * 1024 + t * 4;
    int4 d = make_int4(0, 0, 0, 0);
    if (n0 < NN) d = *(const int4*)&din[n0];
    int tsum = d.x + d.y + d.z + d.w;
    part[t] = tsum;
    __syncthreads();
    for (int off = 1; off < 256; off <<= 1) {
        int v = (t >= off) ? part[t - off] : 0;
        __syncthreads();
        part[t] += v;
        __syncthreads();
    }
    if (n0 < NN) {
        int o = bases[blockIdx.x] + part[t] - tsum;
        *(int4*)&offs[n0] = make_int4(o, o + d.x, o + d.x + d.y, o + d.x + d.y + d.z);
    }
}

// rel8[b][n] = sum over b' < b of histD[b'][n]  (<= deg_in, fits uint8)
__global__ __launch_bounds__(256) void k_blockbase(const unsigned int* __restrict__ histD,
                                                   unsigned char* __restrict__ rel8) {
    int n = blockIdx.x * blockDim.x + threadIdx.x;
    if (n >= NN) return;
    int wi = n >> 2, sh = (n & 3) * 8;
    unsigned int run = 0;
    for (int b = 0; b < NB; ++b) {
        rel8[(size_t)b * NN + n] = (unsigned char)run;
        run += (histD[(size_t)b * SLICE_W + wi] >> sh) & 0xFFu;
    }
}

// Atomic-free CSC scatter (uint16 entries): local position from LDS packed-byte cursor
__global__ __launch_bounds__(512) void k_scatter2(const int4* __restrict__ src4,
                                                  const int4* __restrict__ dst4,
                                                  const int* __restrict__ offs,
                                                  const unsigned char* __restrict__ rel8,
                                                  unsigned short* __restrict__ csc) {
    __shared__ unsigned int lc[SLICE_W];   // 50 KB
    for (int i = threadIdx.x; i < SLICE_W; i += 512) lc[i] = 0u;
    __syncthreads();
    int b = blockIdx.x;
    const unsigned char* rel = rel8 + (size_t)b * NN;
    int beg = b * CHUNK4, end = min(beg + CHUNK4, NE4);
    for (int i = beg + threadIdx.x; i < end; i += 512) {
        int4 s = src4[i];
        int4 d = dst4[i];
#pragma unroll
        for (int j = 0; j < 4; ++j) {
            int dd = (j == 0) ? d.x : (j == 1) ? d.y : (j == 2) ? d.z : d.w;
            int ss = (j == 0) ? s.x : (j == 1) ? s.y : (j == 2) ? s.z : s.w;
            int sh = (dd & 3) * 8;
            unsigned int old = atomicAdd(&lc[dd >> 2], 1u << sh);
            int local = (old >> sh) & 0xFF;
            csc[offs[dd] + rel[dd] + local] = (unsigned short)ss;
        }
    }
}

// Y[r][:] = fp16((X[r][:] @ W) * cs[r]) ; W staged fp16 in LDS (40KB total -> 4 blocks/CU)
__global__ __launch_bounds__(256) void k_matmul_cs(const float* __restrict__ X,
                                                   const float* __restrict__ W,
                                                   const float* __restrict__ cs,
                                                   __half* __restrict__ Y, int nrows) {
    __shared__ __half sW[DIM * DIM];  // 32 KB
    __shared__ float sX[16][DIM];     //  8 KB
    for (int i = threadIdx.x * 4; i < DIM * DIM; i += 256 * 4) {
        float4 w4 = *(const float4*)&W[i];
        *(__half2*)&sW[i]     = __float22half2_rn(make_float2(w4.x, w4.y));
        *(__half2*)&sW[i + 2] = __float22half2_rn(make_float2(w4.z, w4.w));
    }
    int rl = threadIdx.x >> 6;
    int c = (threadIdx.x & 63) * 2;
    int ngroups = (nrows + 15) >> 4;
    for (int g = blockIdx.x; g < ngroups; g += gridDim.x) {
        __syncthreads();
        {
            int row = threadIdx.x >> 4;
            int col = (threadIdx.x & 15) * 8;
            int rr = min(g * 16 + row, nrows - 1);
            const float* xp = X + (size_t)rr * DIM + col;
            *(float4*)&sX[row][col] = *(const float4*)xp;
            *(float4*)&sX[row][col + 4] = *(const float4*)(xp + 4);
        }
        __syncthreads();
        float acc[4][2] = {};
#pragma unroll 4
        for (int k = 0; k < DIM; ++k) {
            float2 w = __half22float2(*(const __half2*)&sW[k * DIM + c]);
            float x0 = sX[rl * 4 + 0][k];
            float x1 = sX[rl * 4 + 1][k];
            float x2 = sX[rl * 4 + 2][k];
            float x3 = sX[rl * 4 + 3][k];
            acc[0][0] = fmaf(x0, w.x, acc[0][0]); acc[0][1] = fmaf(x0, w.y, acc[0][1]);
            acc[1][0] = fmaf(x1, w.x, acc[1][0]); acc[1][1] = fmaf(x1, w.y, acc[1][1]);
            acc[2][0] = fmaf(x2, w.x, acc[2][0]); acc[2][1] = fmaf(x2, w.y, acc[2][1]);
            acc[3][0] = fmaf(x3, w.x, acc[3][0]); acc[3][1] = fmaf(x3, w.y, acc[3][1]);
        }
#pragma unroll
        for (int j = 0; j < 4; ++j) {
            int r = g * 16 + rl * 4 + j;
            if (r < nrows) {
                float s = cs[r];
                __half2 hv = __float22half2_rn(make_float2(acc[j][0] * s, acc[j][1] * s));
                *(__half2*)&Y[(size_t)r * DIM + c] = hv;
            }
        }
    }
}

// Full-row aggregate, 8-deep edge unroll (R12-proven): 32 lanes x 8B cover the
// 256B row, wave-halves take even/odd edge slots, 8 gathers in flight per half.
__global__ __launch_bounds__(256) void k_aggregate(const __half* __restrict__ hs,
                                                   const unsigned short* __restrict__ csc,
                                                   const int* __restrict__ offs,
                                                   const int* __restrict__ din,
                                                   const float* __restrict__ cd,
                                                   const float* __restrict__ bias,
                                                   float* __restrict__ out) {
    int wid = threadIdx.x >> 6;
    int lane = threadIdx.x & 63;
    int h = lane >> 5;        // edge-slot parity
    int l = lane & 31;        // dim group: dims l*4 .. l*4+3
    int d = blockIdx.x * 4 + wid;   // NN % 4 == 0
    int beg = offs[d];
    int end = beg + din[d];
    const __half* base = hs + l * 4;
    float a0 = 0.f, a1 = 0.f, a2 = 0.f, a3 = 0.f;
    float b0 = 0.f, b1 = 0.f, b2 = 0.f, b3 = 0.f;
    float c0 = 0.f, c1 = 0.f, c2 = 0.f, c3 = 0.f;
    float e0 = 0.f, e1 = 0.f, e2 = 0.f, e3 = 0.f;
    int i = beg + h;
    for (; i + 14 < end; i += 16) {
        int sI[8];
#pragma unroll
        for (int j = 0; j < 8; ++j) sI[j] = csc[i + 2 * j];
        short4 vI[8];
#pragma unroll
        for (int j = 0; j < 8; ++j) vI[j] = *(const short4*)(base + (size_t)sI[j] * DIM);
#pragma unroll
        for (int j = 0; j < 8; j += 4) {
            float2 x0 = __half22float2(*(const __half2*)&vI[j].x);
            float2 x1 = __half22float2(*(const __half2*)&vI[j].z);
            float2 y0 = __half22float2(*(const __half2*)&vI[j + 1].x);
            float2 y1 = __half22float2(*(const __half2*)&vI[j + 1].z);
            float2 z0 = __half22float2(*(const __half2*)&vI[j + 2].x);
            float2 z1 = __half22float2(*(const __half2*)&vI[j + 2].z);
            float2 w0 = __half22float2(*(const __half2*)&vI[j + 3].x);
            float2 w1 = __half22float2(*(const __half2*)&vI[j + 3].z);
            a0 += x0.x; a1 += x0.y; a2 += x1.x; a3 += x1.y;
            b0 += y0.x; b1 += y0.y; b2 += y1.x; b3 += y1.y;
            c0 += z0.x; c1 += z0.y; c2 += z1.x; c3 += z1.y;
            e0 += w0.x; e1 += w0.y; e2 += w1.x; e3 += w1.y;
        }
    }
    for (; i + 6 < end; i += 8) {
        int s0 = csc[i], s1 = csc[i + 2], s2 = csc[i + 4], s3 = csc[i + 6];
        short4 v0 = *(const short4*)(base + (size_t)s0 * DIM);
        short4 v1 = *(const short4*)(base + (size_t)s1 * DIM);
        short4 v2 = *(const short4*)(base + (size_t)s2 * DIM);
        short4 v3 = *(const short4*)(base + (size_t)s3 * DIM);
        float2 x0 = __half22float2(*(const __half2*)&v0.x);
        float2 x1 = __half22float2(*(const __half2*)&v0.z);
        float2 y0 = __half22float2(*(const __half2*)&v1.x);
        float2 y1 = __half22float2(*(const __half2*)&v1.z);
        float2 z0 = __half22float2(*(const __half2*)&v2.x);
        float2 z1 = __half22float2(*(const __half2*)&v2.z);
        float2 w0 = __half22float2(*(const __half2*)&v3.x);
        float2 w1 = __half22float2(*(const __half2*)&v3.z);
        a0 += x0.x; a1 += x0.y; a2 += x1.x; a3 += x1.y;
        b0 += y0.x; b1 += y0.y; b2 += y1.x; b3 += y1.y;
        c0 += z0.x; c1 += z0.y; c2 += z1.x; c3 += z1.y;
        e0 += w0.x; e1 += w0.y; e2 += w1.x; e3 += w1.y;
    }
    for (; i < end; i += 2) {
        int s = csc[i];
        short4 v = *(const short4*)(base + (size_t)s * DIM);
        float2 x0 = __half22float2(*(const __half2*)&v.x);
        float2 x1 = __half22float2(*(const __half2*)&v.z);
        a0 += x0.x; a1 += x0.y; a2 += x1.x; a3 += x1.y;
    }
    a0 += b0 + c0 + e0; a1 += b1 + c1 + e1;
    a2 += b2 + c2 + e2; a3 += b3 + c3 + e3;
    a0 += __shfl(a0, lane ^ 32);
    a1 += __shfl(a1, lane ^ 32);
    a2 += __shfl(a2, lane ^ 32);
    a3 += __shfl(a3, lane ^ 32);
    if (h == 0) {
        float c = cd[d];
        float4 bv = *(const float4*)&bias[l * 4];
        float4 o;
        o.x = fmaxf(fmaf(a0, c, bv.x), 0.f);
        o.y = fmaxf(fmaf(a1, c, bv.y), 0.f);
        o.z = fmaxf(fmaf(a2, c, bv.z), 0.f);
        o.w = fmaxf(fmaf(a3, c, bv.w), 0.f);
        *(float4*)&out[(size_t)d * DIM + l * 4] = o;
    }
}

// R[u][:] = tanh(h[users[u]] @ Ws1 + bs1) @ Ws2 + bs2
__global__ __launch_bounds__(256) void k_sr_head(const float* __restrict__ h,
                                                 const int* __restrict__ users,
                                                 const float* __restrict__ Ws1,
                                                 const float* __restrict__ bs1,
                                                 const float* __restrict__ Ws2,
                                                 const float* __restrict__ bs2,
                                                 float* __restrict__ R, int nu) {
    __shared__ float sW1[DIM * 64];
    __shared__ float sW2[64 * 64];
    __shared__ float sU[4][DIM];
    __shared__ float sT[4][64];
    for (int i = threadIdx.x * 4; i < DIM * 64; i += 256 * 4)
        *(float4*)&sW1[i] = *(const float4*)&Ws1[i];
    for (int i = threadIdx.x * 4; i < 64 * 64; i += 256 * 4)
        *(float4*)&sW2[i] = *(const float4*)&Ws2[i];
    int ul = threadIdx.x >> 6;
    int c = threadIdx.x & 63;
    for (int base = blockIdx.x * 4; base < nu; base += gridDim.x * 4) {
        int u = base + ul;
        __syncthreads();
        if (u < nu) {
            int node = users[u];
            *(float2*)&sU[ul][c * 2] = *(const float2*)&h[(size_t)node * DIM + c * 2];
        }
        __syncthreads();
        float t = 0.f;
        if (u < nu) {
            float acc = bs1[c];
#pragma unroll 8
            for (int k = 0; k < DIM; ++k) acc = fmaf(sU[ul][k], sW1[k * 64 + c], acc);
            t = tanhf(acc);
        }
        sT[ul][c] = t;
        __syncthreads();
        if (u < nu) {
            float acc = bs2[c];
#pragma unroll 8
            for (int k = 0; k < 64; ++k) acc = fmaf(sT[ul][k], sW2[k * 64 + c], acc);
            R[(size_t)u * 64 + c] = acc;
        }
    }
}

extern "C" void kernel_launch(void* const* d_in, const int* in_sizes, int n_in,
                              void* d_out, int out_size, void* d_ws, size_t ws_size,
                              hipStream_t stream) {
    const float* features = (const float*)d_in[0];
    const float* W0  = (const float*)d_in[1];
    const float* b0  = (const float*)d_in[2];
    const float* W1  = (const float*)d_in[3];
    const float* b1  = (const float*)d_in[4];
    const float* Ws1 = (const float*)d_in[5];
    const float* bs1 = (const float*)d_in[6];
    const float* Ws2 = (const float*)d_in[7];
    const float* bs2 = (const float*)d_in[8];
    const int* src   = (const int*)d_in[9];
    const int* dst   = (const int*)d_in[10];
    const int* users = (const int*)d_in[11];

    float* R = (float*)d_out;
    float* H = (float*)d_out + (size_t)NU * 64;

    char* ws = (char*)d_ws;
    __half* hsA  = (__half*)(ws + 0);                      // 12.8 MB
    unsigned int* histD = (unsigned int*)(ws + 0);         // 12.8 MB (256 x 50000B)
    unsigned int* histS = (unsigned int*)(ws + 12800000);  // 12.8 MB
    unsigned char* rel8 = (unsigned char*)(ws + 12800000); // 12.8 MB (overlays dead histS)
    unsigned short* csc = (unsigned short*)(ws + 25600000);//  3.2 MB (uint16 ids)
    int*   din   = (int*)  (ws + 28800000);
    float* cs    = (float*)(ws + 29000000);
    float* cd    = (float*)(ws + 29200000);
    int*   offs  = (int*)  (ws + 29400000);
    int*   partials = (int*)(ws + 29600000);
    int*   bases    = (int*)(ws + 29601024);               // end ~29.6 MB

    k_hist<<<2 * NB, 512, 0, stream>>>((const int4*)src, (const int4*)dst, histD, histS);
    k_reduce_norms<<<NSC, 256, 0, stream>>>(histD, histS, din, cs, cd, partials);
    k_scan2<<<1, 64, 0, stream>>>(partials, bases);
    k_scan3<<<NSC, 256, 0, stream>>>(din, bases, offs);
    k_blockbase<<<(NN + 255) / 256, 256, 0, stream>>>(histD, rel8);
    k_scatter2<<<NB, 512, 0, stream>>>((const int4*)src, (const int4*)dst, offs, rel8, csc);

    // layer 1
    k_matmul_cs<<<1024, 256, 0, stream>>>(features, W0, cs, hsA, NN);
    k_aggregate<<<12500, 256, 0, stream>>>(hsA, csc, offs, din, cd, b0, H);

    // layer 2
    k_matmul_cs<<<1024, 256, 0, stream>>>(H, W1, cs, hsA, NN);
    k_aggregate<<<12500, 256, 0, stream>>>(hsA, csc, offs, din, cd, b1, H);

    // SR head
    k_sr_head<<<625, 256, 0, stream>>>(H, users, Ws1, bs1, Ws2, bs2, R, NU);
}

// Round 16
// 285.195 us; speedup vs baseline: 1.3806x; 1.0213x over previous
//
#include <hip/hip_runtime.h>
#include <hip/hip_bf16.h>
#include <hip/hip_fp16.h>

#define NN 50000
#define NE 1600000
#define DIM 128
#define NU 10000
#define NB 256           // histogram/scatter chunks
#define SLICE_W 12500    // NN/4 packed-uint8 words per slice
#define NE4 (NE / 4)
#define CHUNK4 ((NE4 + NB - 1) / NB)   // int4 per block
#define NRB 98           // reduce/scan blocks: ceil(NN/512)

// Fused per-chunk packed-uint8 histograms: blocks [0,NB) -> dst, [NB,2NB) -> src
__global__ __launch_bounds__(1024) void k_hist(const int4* __restrict__ src4,
                                               const int4* __restrict__ dst4,
                                               unsigned int* __restrict__ histD,
                                               unsigned int* __restrict__ histS) {
    __shared__ unsigned int lh[SLICE_W];   // 50 KB
    for (int i = threadIdx.x; i < SLICE_W; i += 1024) lh[i] = 0u;
    __syncthreads();
    int b = blockIdx.x & (NB - 1);
    const int4* idx4 = (blockIdx.x < NB) ? dst4 : src4;
    unsigned int* out = ((blockIdx.x < NB) ? histD : histS) + (size_t)b * SLICE_W;
    int beg = b * CHUNK4, end = min(beg + CHUNK4, NE4);
    for (int i = beg + threadIdx.x; i < end; i += 1024) {
        int4 v = idx4[i];
        atomicAdd(&lh[v.x >> 2], 1u << ((v.x & 3) * 8));
        atomicAdd(&lh[v.y >> 2], 1u << ((v.y & 3) * 8));
        atomicAdd(&lh[v.z >> 2], 1u << ((v.z & 3) * 8));
        atomicAdd(&lh[v.w >> 2], 1u << ((v.w & 3) * 8));
    }
    __syncthreads();
    for (int i = threadIdx.x; i < SLICE_W; i += 1024) out[i] = lh[i];
}

// 98 blocks x 256 thr: block covers 128 wi (512 nodes); 2-way split of the b-loop.
__global__ __launch_bounds__(256) void k_reduce_norms(const unsigned int* __restrict__ histD,
                                                      const unsigned int* __restrict__ histS,
                                                      int* __restrict__ din,
                                                      float* __restrict__ cs, float* __restrict__ cd,
                                                      int* __restrict__ partials) {
    __shared__ unsigned int part8[128][8];  // group-1 partial sums, 4 KB
    __shared__ int red[256];
    int wl = threadIdx.x & 127;
    int g = threadIdx.x >> 7;               // 0 or 1
    int wi = blockIdx.x * 128 + wl;
    unsigned int d0 = 0, d1 = 0, d2 = 0, d3 = 0, s0 = 0, s1 = 0, s2 = 0, s3 = 0;
    if (wi < SLICE_W) {
        for (int b = g * 128; b < g * 128 + 128; ++b) {
            unsigned int wd = histD[(size_t)b * SLICE_W + wi];
            unsigned int ws = histS[(size_t)b * SLICE_W + wi];
            d0 += wd & 0xFFu; d1 += (wd >> 8) & 0xFFu; d2 += (wd >> 16) & 0xFFu; d3 += wd >> 24;
            s0 += ws & 0xFFu; s1 += (ws >> 8) & 0xFFu; s2 += (ws >> 16) & 0xFFu; s3 += ws >> 24;
        }
    }
    red[threadIdx.x] = (int)(d0 + d1 + d2 + d3);
    if (g == 1) {
        part8[wl][0] = d0; part8[wl][1] = d1; part8[wl][2] = d2; part8[wl][3] = d3;
        part8[wl][4] = s0; part8[wl][5] = s1; part8[wl][6] = s2; part8[wl][7] = s3;
    }
    __syncthreads();
    if (g == 0 && wi < SLICE_W) {
        d0 += part8[wl][0]; d1 += part8[wl][1]; d2 += part8[wl][2]; d3 += part8[wl][3];
        s0 += part8[wl][4]; s1 += part8[wl][5]; s2 += part8[wl][6]; s3 += part8[wl][7];
        int n = wi * 4;
        *(int4*)&din[n] = make_int4(d0, d1, d2, d3);
        float4 vcd, vcs;
        vcd.x = rsqrtf(fmaxf((float)d0, 1.f)); vcd.y = rsqrtf(fmaxf((float)d1, 1.f));
        vcd.z = rsqrtf(fmaxf((float)d2, 1.f)); vcd.w = rsqrtf(fmaxf((float)d3, 1.f));
        vcs.x = rsqrtf(fmaxf((float)s0, 1.f)); vcs.y = rsqrtf(fmaxf((float)s1, 1.f));
        vcs.z = rsqrtf(fmaxf((float)s2, 1.f)); vcs.w = rsqrtf(fmaxf((float)s3, 1.f));
        *(float4*)&cd[n] = vcd;
        *(float4*)&cs[n] = vcs;
    }
    for (int off = 128; off > 0; off >>= 1) {
        if (threadIdx.x < off) red[threadIdx.x] += red[threadIdx.x + off];
        __syncthreads();
    }
    if (threadIdx.x == 0) partials[blockIdx.x] = red[0];
}

// Exclusive scan of NRB=98 partials: lane handles pair (2l, 2l+1)
__global__ __launch_bounds__(64) void k_scan2(const int* __restrict__ partials,
                                              int* __restrict__ bases) {
    int lane = threadIdx.x;
    int p0 = (2 * lane < NRB) ? partials[2 * lane] : 0;
    int p1 = (2 * lane + 1 < NRB) ? partials[2 * lane + 1] : 0;
    int pair = p0 + p1;
    int s = pair;
    for (int off = 1; off < 64; off <<= 1) {
        int n = __shfl_up(s, off);
        if (lane >= off) s += n;
    }
    int excl = s - pair;
    if (2 * lane < NRB) bases[2 * lane] = excl;
    if (2 * lane + 1 < NRB) bases[2 * lane + 1] = excl + p0;
}

// 98 blocks x 128 thr: 512-node exclusive scan + base -> offs
__global__ __launch_bounds__(128) void k_scan3(const int* __restrict__ din,
                                               const int* __restrict__ bases,
                                               int* __restrict__ offs) {
    __shared__ int part[128];
    int t = threadIdx.x;
    int n0 = blockIdx.x * 512 + t * 4;
    int4 d = make_int4(0, 0, 0, 0);
    if (n0 < NN) d = *(const int4*)&din[n0];
    int tsum = d.x + d.y + d.z + d.w;
    part[t] = tsum;
    __syncthreads();
    for (int off = 1; off < 128; off <<= 1) {
        int v = (t >= off) ? part[t - off] : 0;
        __syncthreads();
        part[t] += v;
        __syncthreads();
    }
    if (n0 < NN) {
        int o = bases[blockIdx.x] + part[t] - tsum;
        *(int4*)&offs[n0] = make_int4(o, o + d.x, o + d.x + d.y, o + d.x + d.y + d.z);
    }
}

// rel8[b][n] = sum over b' < b of histD[b'][n]  (<= deg_in, fits uint8)
__global__ __launch_bounds__(256) void k_blockbase(const unsigned int* __restrict__ histD,
                                                   unsigned char* __restrict__ rel8) {
    int n = blockIdx.x * blockDim.x + threadIdx.x;
    if (n >= NN) return;
    int wi = n >> 2, sh = (n & 3) * 8;
    unsigned int run = 0;
    for (int b = 0; b < NB; ++b) {
        rel8[(size_t)b * NN + n] = (unsigned char)run;
        run += (histD[(size_t)b * SLICE_W + wi] >> sh) & 0xFFu;
    }
}

// Atomic-free CSC scatter (uint16 entries): local position from LDS packed-byte cursor
__global__ __launch_bounds__(1024) void k_scatter2(const int4* __restrict__ src4,
                                                   const int4* __restrict__ dst4,
                                                   const int* __restrict__ offs,
                                                   const unsigned char* __restrict__ rel8,
                                                   unsigned short* __restrict__ csc) {
    __shared__ unsigned int lc[SLICE_W];   // 50 KB
    for (int i = threadIdx.x; i < SLICE_W; i += 1024) lc[i] = 0u;
    __syncthreads();
    int b = blockIdx.x;
    const unsigned char* rel = rel8 + (size_t)b * NN;
    int beg = b * CHUNK4, end = min(beg + CHUNK4, NE4);
    for (int i = beg + threadIdx.x; i < end; i += 1024) {
        int4 s = src4[i];
        int4 d = dst4[i];
#pragma unroll
        for (int j = 0; j < 4; ++j) {
            int dd = (j == 0) ? d.x : (j == 1) ? d.y : (j == 2) ? d.z : d.w;
            int ss = (j == 0) ? s.x : (j == 1) ? s.y : (j == 2) ? s.z : s.w;
            int sh = (dd & 3) * 8;
            unsigned int old = atomicAdd(&lc[dd >> 2], 1u << sh);
            int local = (old >> sh) & 0xFF;
            csc[offs[dd] + rel[dd] + local] = (unsigned short)ss;
        }
    }
}

// Y[r][:] = fp16((X[r][:] @ W) * cs[r]) ; W staged fp16 in LDS (40KB total -> 4 blocks/CU)
__global__ __launch_bounds__(256) void k_matmul_cs(const float* __restrict__ X,
                                                   const float* __restrict__ W,
                                                   const float* __restrict__ cs,
                                                   __half* __restrict__ Y, int nrows) {
    __shared__ __half sW[DIM * DIM];  // 32 KB
    __shared__ float sX[16][DIM];     //  8 KB
    for (int i = threadIdx.x * 4; i < DIM * DIM; i += 256 * 4) {
        float4 w4 = *(const float4*)&W[i];
        *(__half2*)&sW[i]     = __float22half2_rn(make_float2(w4.x, w4.y));
        *(__half2*)&sW[i + 2] = __float22half2_rn(make_float2(w4.z, w4.w));
    }
    int rl = threadIdx.x >> 6;
    int c = (threadIdx.x & 63) * 2;
    int ngroups = (nrows + 15) >> 4;
    for (int g = blockIdx.x; g < ngroups; g += gridDim.x) {
        __syncthreads();
        {
            int row = threadIdx.x >> 4;
            int col = (threadIdx.x & 15) * 8;
            int rr = min(g * 16 + row, nrows - 1);
            const float* xp = X + (size_t)rr * DIM + col;
            *(float4*)&sX[row][col] = *(const float4*)xp;
            *(float4*)&sX[row][col + 4] = *(const float4*)(xp + 4);
        }
        __syncthreads();
        float acc[4][2] = {};
#pragma unroll 4
        for (int k = 0; k < DIM; ++k) {
            float2 w = __half22float2(*(const __half2*)&sW[k * DIM + c]);
            float x0 = sX[rl * 4 + 0][k];
            float x1 = sX[rl * 4 + 1][k];
            float x2 = sX[rl * 4 + 2][k];
            float x3 = sX[rl * 4 + 3][k];
            acc[0][0] = fmaf(x0, w.x, acc[0][0]); acc[0][1] = fmaf(x0, w.y, acc[0][1]);
            acc[1][0] = fmaf(x1, w.x, acc[1][0]); acc[1][1] = fmaf(x1, w.y, acc[1][1]);
            acc[2][0] = fmaf(x2, w.x, acc[2][0]); acc[2][1] = fmaf(x2, w.y, acc[2][1]);
            acc[3][0] = fmaf(x3, w.x, acc[3][0]); acc[3][1] = fmaf(x3, w.y, acc[3][1]);
        }
#pragma unroll
        for (int j = 0; j < 4; ++j) {
            int r = g * 16 + rl * 4 + j;
            if (r < nrows) {
                float s = cs[r];
                __half2 hv = __float22half2_rn(make_float2(acc[j][0] * s, acc[j][1] * s));
                *(__half2*)&Y[(size_t)r * DIM + c] = hv;
            }
        }
    }
}

// Full-row aggregate, 8-deep edge unroll (R12-proven)
__global__ __launch_bounds__(256) void k_aggregate(const __half* __restrict__ hs,
                                                   const unsigned short* __restrict__ csc,
                                                   const int* __restrict__ offs,
                                                   const int* __restrict__ din,
                                                   const float* __restrict__ cd,
                                                   const float* __restrict__ bias,
                                                   float* __restrict__ out) {
    int wid = threadIdx.x >> 6;
    int lane = threadIdx.x & 63;
    int h = lane >> 5;
    int l = lane & 31;
    int d = blockIdx.x * 4 + wid;
    int beg = offs[d];
    int end = beg + din[d];
    const __half* base = hs + l * 4;
    float a0 = 0.f, a1 = 0.f, a2 = 0.f, a3 = 0.f;
    float b0 = 0.f, b1 = 0.f, b2 = 0.f, b3 = 0.f;
    float c0 = 0.f, c1 = 0.f, c2 = 0.f, c3 = 0.f;
    float e0 = 0.f, e1 = 0.f, e2 = 0.f, e3 = 0.f;
    int i = beg + h;
    for (; i + 14 < end; i += 16) {
        int sI[8];
#pragma unroll
        for (int j = 0; j < 8; ++j) sI[j] = csc[i + 2 * j];
        short4 vI[8];
#pragma unroll
        for (int j = 0; j < 8; ++j) vI[j] = *(const short4*)(base + (size_t)sI[j] * DIM);
#pragma unroll
        for (int j = 0; j < 8; j += 4) {
            float2 x0 = __half22float2(*(const __half2*)&vI[j].x);
            float2 x1 = __half22float2(*(const __half2*)&vI[j].z);
            float2 y0 = __half22float2(*(const __half2*)&vI[j + 1].x);
            float2 y1 = __half22float2(*(const __half2*)&vI[j + 1].z);
            float2 z0 = __half22float2(*(const __half2*)&vI[j + 2].x);
            float2 z1 = __half22float2(*(const __half2*)&vI[j + 2].z);
            float2 w0 = __half22float2(*(const __half2*)&vI[j + 3].x);
            float2 w1 = __half22float2(*(const __half2*)&vI[j + 3].z);
            a0 += x0.x; a1 += x0.y; a2 += x1.x; a3 += x1.y;
            b0 += y0.x; b1 += y0.y; b2 += y1.x; b3 += y1.y;
            c0 += z0.x; c1 += z0.y; c2 += z1.x; c3 += z1.y;
            e0 += w0.x; e1 += w0.y; e2 += w1.x; e3 += w1.y;
        }
    }
    for (; i + 6 < end; i += 8) {
        int s0 = csc[i], s1 = csc[i + 2], s2 = csc[i + 4], s3 = csc[i + 6];
        short4 v0 = *(const short4*)(base + (size_t)s0 * DIM);
        short4 v1 = *(const short4*)(base + (size_t)s1 * DIM);
        short4 v2 = *(const short4*)(base + (size_t)s2 * DIM);
        short4 v3 = *(const short4*)(base + (size_t)s3 * DIM);
        float2 x0 = __half22float2(*(const __half2*)&v0.x);
        float2 x1 = __half22float2(*(const __half2*)&v0.z);
        float2 y0 = __half22float2(*(const __half2*)&v1.x);
        float2 y1 = __half22float2(*(const __half2*)&v1.z);
        float2 z0 = __half22float2(*(const __half2*)&v2.x);
        float2 z1 = __half22float2(*(const __half2*)&v2.z);
        float2 w0 = __half22float2(*(const __half2*)&v3.x);
        float2 w1 = __half22float2(*(const __half2*)&v3.z);
        a0 += x0.x; a1 += x0.y; a2 += x1.x; a3 += x1.y;
        b0 += y0.x; b1 += y0.y; b2 += y1.x; b3 += y1.y;
        c0 += z0.x; c1 += z0.y; c2 += z1.x; c3 += z1.y;
        e0 += w0.x; e1 += w0.y; e2 += w1.x; e3 += w1.y;
    }
    for (; i < end; i += 2) {
        int s = csc[i];
        short4 v = *(const short4*)(base + (size_t)s * DIM);
        float2 x0 = __half22float2(*(const __half2*)&v.x);
        float2 x1 = __half22float2(*(const __half2*)&v.z);
        a0 += x0.x; a1 += x0.y; a2 += x1.x; a3 += x1.y;
    }
    a0 += b0 + c0 + e0; a1 += b1 + c1 + e1;
    a2 += b2 + c2 + e2; a3 += b3 + c3 + e3;
    a0 += __shfl(a0, lane ^ 32);
    a1 += __shfl(a1, lane ^ 32);
    a2 += __shfl(a2, lane ^ 32);
    a3 += __shfl(a3, lane ^ 32);
    if (h == 0) {
        float c = cd[d];
        float4 bv = *(const float4*)&bias[l * 4];
        float4 o;
        o.x = fmaxf(fmaf(a0, c, bv.x), 0.f);
        o.y = fmaxf(fmaf(a1, c, bv.y), 0.f);
        o.z = fmaxf(fmaf(a2, c, bv.z), 0.f);
        o.w = fmaxf(fmaf(a3, c, bv.w), 0.f);
        *(float4*)&out[(size_t)d * DIM + l * 4] = o;
    }
}

// R[u][:] = tanh(h[users[u]] @ Ws1 + bs1) @ Ws2 + bs2
__global__ __launch_bounds__(256) void k_sr_head(const float* __restrict__ h,
                                                 const int* __restrict__ users,
                                                 const float* __restrict__ Ws1,
                                                 const float* __restrict__ bs1,
                                                 const float* __restrict__ Ws2,
                                                 const float* __restrict__ bs2,
                                                 float* __restrict__ R, int nu) {
    __shared__ float sW1[DIM * 64];
    __shared__ float sW2[64 * 64];
    __shared__ float sU[4][DIM];
    __shared__ float sT[4][64];
    for (int i = threadIdx.x * 4; i < DIM * 64; i += 256 * 4)
        *(float4*)&sW1[i] = *(const float4*)&Ws1[i];
    for (int i = threadIdx.x * 4; i < 64 * 64; i += 256 * 4)
        *(float4*)&sW2[i] = *(const float4*)&Ws2[i];
    int ul = threadIdx.x >> 6;
    int c = threadIdx.x & 63;
    for (int base = blockIdx.x * 4; base < nu; base += gridDim.x * 4) {
        int u = base + ul;
        __syncthreads();
        if (u < nu) {
            int node = users[u];
            *(float2*)&sU[ul][c * 2] = *(const float2*)&h[(size_t)node * DIM + c * 2];
        }
        __syncthreads();
        float t = 0.f;
        if (u < nu) {
            float acc = bs1[c];
#pragma unroll 8
            for (int k = 0; k < DIM; ++k) acc = fmaf(sU[ul][k], sW1[k * 64 + c], acc);
            t = tanhf(acc);
        }
        sT[ul][c] = t;
        __syncthreads();
        if (u < nu) {
            float acc = bs2[c];
#pragma unroll 8
            for (int k = 0; k < 64; ++k) acc = fmaf(sT[ul][k], sW2[k * 64 + c], acc);
            R[(size_t)u * 64 + c] = acc;
        }
    }
}

extern "C" void kernel_launch(void* const* d_in, const int* in_sizes, int n_in,
                              void* d_out, int out_size, void* d_ws, size_t ws_size,
                              hipStream_t stream) {
    const float* features = (const float*)d_in[0];
    const float* W0  = (const float*)d_in[1];
    const float* b0  = (const float*)d_in[2];
    const float* W1  = (const float*)d_in[3];
    const float* b1  = (const float*)d_in[4];
    const float* Ws1 = (const float*)d_in[5];
    const float* bs1 = (const float*)d_in[6];
    const float* Ws2 = (const float*)d_in[7];
    const float* bs2 = (const float*)d_in[8];
    const int* src   = (const int*)d_in[9];
    const int* dst   = (const int*)d_in[10];
    const int* users = (const int*)d_in[11];

    float* R = (float*)d_out;
    float* H = (float*)d_out + (size_t)NU * 64;

    char* ws = (char*)d_ws;
    __half* hsA  = (__half*)(ws + 0);                      // 12.8 MB
    unsigned int* histD = (unsigned int*)(ws + 0);         // 12.8 MB (256 x 50000B)
    unsigned int* histS = (unsigned int*)(ws + 12800000);  // 12.8 MB
    unsigned char* rel8 = (unsigned char*)(ws + 12800000); // 12.8 MB (overlays dead histS)
    unsigned short* csc = (unsigned short*)(ws + 25600000);//  3.2 MB (uint16 ids)
    int*   din   = (int*)  (ws + 28800000);
    float* cs    = (float*)(ws + 29000000);
    float* cd    = (float*)(ws + 29200000);
    int*   offs  = (int*)  (ws + 29400000);
    int*   partials = (int*)(ws + 29600000);
    int*   bases    = (int*)(ws + 29601024);               // end ~29.6 MB

    k_hist<<<2 * NB, 1024, 0, stream>>>((const int4*)src, (const int4*)dst, histD, histS);
    k_reduce_norms<<<NRB, 256, 0, stream>>>(histD, histS, din, cs, cd, partials);
    k_scan2<<<1, 64, 0, stream>>>(partials, bases);
    k_scan3<<<NRB, 128, 0, stream>>>(din, bases, offs);
    k_blockbase<<<(NN + 255) / 256, 256, 0, stream>>>(histD, rel8);
    k_scatter2<<<NB, 1024, 0, stream>>>((const int4*)src, (const int4*)dst, offs, rel8, csc);

    // layer 1
    k_matmul_cs<<<1024, 256, 0, stream>>>(features, W0, cs, hsA, NN);
    k_aggregate<<<12500, 256, 0, stream>>>(hsA, csc, offs, din, cd, b0, H);

    // layer 2
    k_matmul_cs<<<1024, 256, 0, stream>>>(H, W1, cs, hsA, NN);
    k_aggregate<<<12500, 256, 0, stream>>>(hsA, csc, offs, din, cd, b1, H);

    // SR head
    k_sr_head<<<625, 256, 0, stream>>>(H, users, Ws1, bs1, Ws2, bs2, R, NU);
}

// Round 17
// 246.967 us; speedup vs baseline: 1.5943x; 1.1548x over previous
//
#include <hip/hip_runtime.h>
#include <hip/hip_bf16.h>
#include <hip/hip_fp16.h>

#define NN 50000
#define NE 1600000
#define DIM 128
#define NU 10000
#define NB 256           // histogram/scatter chunks
#define SLICE_W 12500    // NN/4 packed-uint8 words per slice
#define NE4 (NE / 4)
#define CHUNK4 ((NE4 + NB - 1) / NB)   // int4 per block
#define NRB 98           // reduce/scan blocks: ceil(NN/512)
#define MM_ROWS 64       // rows per mfma-matmul block iteration

typedef __attribute__((ext_vector_type(8))) _Float16 f16x8;
typedef __attribute__((ext_vector_type(4))) float f32x4;

// Fused per-chunk packed-uint8 histograms: blocks [0,NB) -> dst, [NB,2NB) -> src
__global__ __launch_bounds__(1024) void k_hist(const int4* __restrict__ src4,
                                               const int4* __restrict__ dst4,
                                               unsigned int* __restrict__ histD,
                                               unsigned int* __restrict__ histS) {
    __shared__ unsigned int lh[SLICE_W];   // 50 KB
    for (int i = threadIdx.x; i < SLICE_W; i += 1024) lh[i] = 0u;
    __syncthreads();
    int b = blockIdx.x & (NB - 1);
    const int4* idx4 = (blockIdx.x < NB) ? dst4 : src4;
    unsigned int* out = ((blockIdx.x < NB) ? histD : histS) + (size_t)b * SLICE_W;
    int beg = b * CHUNK4, end = min(beg + CHUNK4, NE4);
    for (int i = beg + threadIdx.x; i < end; i += 1024) {
        int4 v = idx4[i];
        atomicAdd(&lh[v.x >> 2], 1u << ((v.x & 3) * 8));
        atomicAdd(&lh[v.y >> 2], 1u << ((v.y & 3) * 8));
        atomicAdd(&lh[v.z >> 2], 1u << ((v.z & 3) * 8));
        atomicAdd(&lh[v.w >> 2], 1u << ((v.w & 3) * 8));
    }
    __syncthreads();
    for (int i = threadIdx.x; i < SLICE_W; i += 1024) out[i] = lh[i];
}

// 98 blocks x 256 thr: block covers 128 wi (512 nodes); 2-way split of the b-loop.
__global__ __launch_bounds__(256) void k_reduce_norms(const unsigned int* __restrict__ histD,
                                                      const unsigned int* __restrict__ histS,
                                                      int* __restrict__ din,
                                                      float* __restrict__ cs, float* __restrict__ cd,
                                                      int* __restrict__ partials) {
    __shared__ unsigned int part8[128][8];
    __shared__ int red[256];
    int wl = threadIdx.x & 127;
    int g = threadIdx.x >> 7;
    int wi = blockIdx.x * 128 + wl;
    unsigned int d0 = 0, d1 = 0, d2 = 0, d3 = 0, s0 = 0, s1 = 0, s2 = 0, s3 = 0;
    if (wi < SLICE_W) {
        for (int b = g * 128; b < g * 128 + 128; ++b) {
            unsigned int wd = histD[(size_t)b * SLICE_W + wi];
            unsigned int ws = histS[(size_t)b * SLICE_W + wi];
            d0 += wd & 0xFFu; d1 += (wd >> 8) & 0xFFu; d2 += (wd >> 16) & 0xFFu; d3 += wd >> 24;
            s0 += ws & 0xFFu; s1 += (ws >> 8) & 0xFFu; s2 += (ws >> 16) & 0xFFu; s3 += ws >> 24;
        }
    }
    red[threadIdx.x] = (int)(d0 + d1 + d2 + d3);
    if (g == 1) {
        part8[wl][0] = d0; part8[wl][1] = d1; part8[wl][2] = d2; part8[wl][3] = d3;
        part8[wl][4] = s0; part8[wl][5] = s1; part8[wl][6] = s2; part8[wl][7] = s3;
    }
    __syncthreads();
    if (g == 0 && wi < SLICE_W) {
        d0 += part8[wl][0]; d1 += part8[wl][1]; d2 += part8[wl][2]; d3 += part8[wl][3];
        s0 += part8[wl][4]; s1 += part8[wl][5]; s2 += part8[wl][6]; s3 += part8[wl][7];
        int n = wi * 4;
        *(int4*)&din[n] = make_int4(d0, d1, d2, d3);
        float4 vcd, vcs;
        vcd.x = rsqrtf(fmaxf((float)d0, 1.f)); vcd.y = rsqrtf(fmaxf((float)d1, 1.f));
        vcd.z = rsqrtf(fmaxf((float)d2, 1.f)); vcd.w = rsqrtf(fmaxf((float)d3, 1.f));
        vcs.x = rsqrtf(fmaxf((float)s0, 1.f)); vcs.y = rsqrtf(fmaxf((float)s1, 1.f));
        vcs.z = rsqrtf(fmaxf((float)s2, 1.f)); vcs.w = rsqrtf(fmaxf((float)s3, 1.f));
        *(float4*)&cd[n] = vcd;
        *(float4*)&cs[n] = vcs;
    }
    for (int off = 128; off > 0; off >>= 1) {
        if (threadIdx.x < off) red[threadIdx.x] += red[threadIdx.x + off];
        __syncthreads();
    }
    if (threadIdx.x == 0) partials[blockIdx.x] = red[0];
}

// 98 blocks x 128 thr: computes own base from partials, then 512-node scan -> offs
__global__ __launch_bounds__(128) void k_scan3(const int* __restrict__ din,
                                               const int* __restrict__ partials,
                                               int* __restrict__ offs) {
    __shared__ int part[128];
    __shared__ int sbase;
    int t = threadIdx.x;
    part[t] = (t < blockIdx.x) ? partials[t] : 0;   // blockIdx.x <= 97 < 128
    __syncthreads();
    for (int off = 64; off > 0; off >>= 1) {
        if (t < off) part[t] += part[t + off];
        __syncthreads();
    }
    if (t == 0) sbase = part[0];
    __syncthreads();
    int base = sbase;
    int n0 = blockIdx.x * 512 + t * 4;
    int4 d = make_int4(0, 0, 0, 0);
    if (n0 < NN) d = *(const int4*)&din[n0];
    int tsum = d.x + d.y + d.z + d.w;
    __syncthreads();
    part[t] = tsum;
    __syncthreads();
    for (int off = 1; off < 128; off <<= 1) {
        int v = (t >= off) ? part[t - off] : 0;
        __syncthreads();
        part[t] += v;
        __syncthreads();
    }
    if (n0 < NN) {
        int o = base + part[t] - tsum;
        *(int4*)&offs[n0] = make_int4(o, o + d.x, o + d.x + d.y, o + d.x + d.y + d.z);
    }
}

// rel8[b][n] = sum over b' < b of histD[b'][n]
__global__ __launch_bounds__(256) void k_blockbase(const unsigned int* __restrict__ histD,
                                                   unsigned char* __restrict__ rel8) {
    int n = blockIdx.x * blockDim.x + threadIdx.x;
    if (n >= NN) return;
    int wi = n >> 2, sh = (n & 3) * 8;
    unsigned int run = 0;
    for (int b = 0; b < NB; ++b) {
        rel8[(size_t)b * NN + n] = (unsigned char)run;
        run += (histD[(size_t)b * SLICE_W + wi] >> sh) & 0xFFu;
    }
}

// Atomic-free CSC scatter (uint16 entries)
__global__ __launch_bounds__(1024) void k_scatter2(const int4* __restrict__ src4,
                                                   const int4* __restrict__ dst4,
                                                   const int* __restrict__ offs,
                                                   const unsigned char* __restrict__ rel8,
                                                   unsigned short* __restrict__ csc) {
    __shared__ unsigned int lc[SLICE_W];
    for (int i = threadIdx.x; i < SLICE_W; i += 1024) lc[i] = 0u;
    __syncthreads();
    int b = blockIdx.x;
    const unsigned char* rel = rel8 + (size_t)b * NN;
    int beg = b * CHUNK4, end = min(beg + CHUNK4, NE4);
    for (int i = beg + threadIdx.x; i < end; i += 1024) {
        int4 s = src4[i];
        int4 d = dst4[i];
#pragma unroll
        for (int j = 0; j < 4; ++j) {
            int dd = (j == 0) ? d.x : (j == 1) ? d.y : (j == 2) ? d.z : d.w;
            int ss = (j == 0) ? s.x : (j == 1) ? s.y : (j == 2) ? s.z : s.w;
            int sh = (dd & 3) * 8;
            unsigned int old = atomicAdd(&lc[dd >> 2], 1u << sh);
            int local = (old >> sh) & 0xFF;
            csc[offs[dd] + rel[dd] + local] = (unsigned short)ss;
        }
    }
}

// MFMA matmul: Y[r][:] = fp16((X[r][:] @ W) * cs[r]).
// Fragment layouts (16x16x32 f16): A lane l: row=l&15, k=(l>>4)*8+j;
// B lane l: col=l&15, k=(l>>4)*8+j; C lane l: col=l&15, row=(l>>4)*4+reg.
__global__ __launch_bounds__(256) void k_matmul_mfma(const float* __restrict__ X,
                                                     const float* __restrict__ W,
                                                     const float* __restrict__ cs,
                                                     __half* __restrict__ Y, int nrows) {
    __shared__ f16x8 sB[8][4][64];   // [colTile][kChunk][lane] : 32 KB
    __shared__ f16x8 sA[4][4][64];   // [rowTile(wave)][kChunk][lane] : 16 KB
    int t = threadIdx.x;
    for (int e = t; e < 8 * 4 * 64; e += 256) {
        int ct = e >> 8;
        int k0 = (e >> 6) & 3;
        int l = e & 63;
        int c = ct * 16 + (l & 15);
        int kb = k0 * 32 + ((l >> 4) << 3);
        f16x8 frag;
#pragma unroll
        for (int j = 0; j < 8; ++j) frag[j] = (_Float16)W[(size_t)(kb + j) * DIM + c];
        sB[ct][k0][l] = frag;
    }
    int wave = t >> 6;
    int l = t & 63;
    int crow = (l >> 4) * 4;
    int ccol = l & 15;
    int ng = (nrows + MM_ROWS - 1) / MM_ROWS;
    for (int g = blockIdx.x; g < ng; g += gridDim.x) {
        int rbase = g * MM_ROWS;
        __syncthreads();   // sB ready (first iter) / previous-iter sA reads done
        for (int e = t; e < 4 * 4 * 64; e += 256) {
            int wt = e >> 8;
            int k0 = (e >> 6) & 3;
            int ll = e & 63;
            int r = min(rbase + wt * 16 + (ll & 15), nrows - 1);
            int kb = k0 * 32 + ((ll >> 4) << 3);
            const float* xp = X + (size_t)r * DIM + kb;
            float4 xa = *(const float4*)xp;
            float4 xb = *(const float4*)(xp + 4);
            f16x8 frag;
            frag[0] = (_Float16)xa.x; frag[1] = (_Float16)xa.y;
            frag[2] = (_Float16)xa.z; frag[3] = (_Float16)xa.w;
            frag[4] = (_Float16)xb.x; frag[5] = (_Float16)xb.y;
            frag[6] = (_Float16)xb.z; frag[7] = (_Float16)xb.w;
            sA[wt][k0][ll] = frag;
        }
        __syncthreads();
        f16x8 a0 = sA[wave][0][l], a1 = sA[wave][1][l];
        f16x8 a2 = sA[wave][2][l], a3 = sA[wave][3][l];
        float csv[4];
#pragma unroll
        for (int j = 0; j < 4; ++j)
            csv[j] = cs[min(rbase + wave * 16 + crow + j, nrows - 1)];
#pragma unroll
        for (int ct = 0; ct < 8; ++ct) {
            f32x4 acc = {0.f, 0.f, 0.f, 0.f};
            acc = __builtin_amdgcn_mfma_f32_16x16x32_f16(a0, sB[ct][0][l], acc, 0, 0, 0);
            acc = __builtin_amdgcn_mfma_f32_16x16x32_f16(a1, sB[ct][1][l], acc, 0, 0, 0);
            acc = __builtin_amdgcn_mfma_f32_16x16x32_f16(a2, sB[ct][2][l], acc, 0, 0, 0);
            acc = __builtin_amdgcn_mfma_f32_16x16x32_f16(a3, sB[ct][3][l], acc, 0, 0, 0);
#pragma unroll
            for (int j = 0; j < 4; ++j) {
                int r = rbase + wave * 16 + crow + j;
                if (r < nrows)
                    Y[(size_t)r * DIM + ct * 16 + ccol] = __float2half(acc[j] * csv[j]);
            }
        }
    }
}

// Full-row aggregate, 8-deep edge unroll (R12-proven)
__global__ __launch_bounds__(256) void k_aggregate(const __half* __restrict__ hs,
                                                   const unsigned short* __restrict__ csc,
                                                   const int* __restrict__ offs,
                                                   const int* __restrict__ din,
                                                   const float* __restrict__ cd,
                                                   const float* __restrict__ bias,
                                                   float* __restrict__ out) {
    int wid = threadIdx.x >> 6;
    int lane = threadIdx.x & 63;
    int h = lane >> 5;
    int l = lane & 31;
    int d = blockIdx.x * 4 + wid;
    int beg = offs[d];
    int end = beg + din[d];
    const __half* base = hs + l * 4;
    float a0 = 0.f, a1 = 0.f, a2 = 0.f, a3 = 0.f;
    float b0 = 0.f, b1 = 0.f, b2 = 0.f, b3 = 0.f;
    float c0 = 0.f, c1 = 0.f, c2 = 0.f, c3 = 0.f;
    float e0 = 0.f, e1 = 0.f, e2 = 0.f, e3 = 0.f;
    int i = beg + h;
    for (; i + 14 < end; i += 16) {
        int sI[8];
#pragma unroll
        for (int j = 0; j < 8; ++j) sI[j] = csc[i + 2 * j];
        short4 vI[8];
#pragma unroll
        for (int j = 0; j < 8; ++j) vI[j] = *(const short4*)(base + (size_t)sI[j] * DIM);
#pragma unroll
        for (int j = 0; j < 8; j += 4) {
            float2 x0 = __half22float2(*(const __half2*)&vI[j].x);
            float2 x1 = __half22float2(*(const __half2*)&vI[j].z);
            float2 y0 = __half22float2(*(const __half2*)&vI[j + 1].x);
            float2 y1 = __half22float2(*(const __half2*)&vI[j + 1].z);
            float2 z0 = __half22float2(*(const __half2*)&vI[j + 2].x);
            float2 z1 = __half22float2(*(const __half2*)&vI[j + 2].z);
            float2 w0 = __half22float2(*(const __half2*)&vI[j + 3].x);
            float2 w1 = __half22float2(*(const __half2*)&vI[j + 3].z);
            a0 += x0.x; a1 += x0.y; a2 += x1.x; a3 += x1.y;
            b0 += y0.x; b1 += y0.y; b2 += y1.x; b3 += y1.y;
            c0 += z0.x; c1 += z0.y; c2 += z1.x; c3 += z1.y;
            e0 += w0.x; e1 += w0.y; e2 += w1.x; e3 += w1.y;
        }
    }
    for (; i + 6 < end; i += 8) {
        int s0 = csc[i], s1 = csc[i + 2], s2 = csc[i + 4], s3 = csc[i + 6];
        short4 v0 = *(const short4*)(base + (size_t)s0 * DIM);
        short4 v1 = *(const short4*)(base + (size_t)s1 * DIM);
        short4 v2 = *(const short4*)(base + (size_t)s2 * DIM);
        short4 v3 = *(const short4*)(base + (size_t)s3 * DIM);
        float2 x0 = __half22float2(*(const __half2*)&v0.x);
        float2 x1 = __half22float2(*(const __half2*)&v0.z);
        float2 y0 = __half22float2(*(const __half2*)&v1.x);
        float2 y1 = __half22float2(*(const __half2*)&v1.z);
        float2 z0 = __half22float2(*(const __half2*)&v2.x);
        float2 z1 = __half22float2(*(const __half2*)&v2.z);
        float2 w0 = __half22float2(*(const __half2*)&v3.x);
        float2 w1 = __half22float2(*(const __half2*)&v3.z);
        a0 += x0.x; a1 += x0.y; a2 += x1.x; a3 += x1.y;
        b0 += y0.x; b1 += y0.y; b2 += y1.x; b3 += y1.y;
        c0 += z0.x; c1 += z0.y; c2 += z1.x; c3 += z1.y;
        e0 += w0.x; e1 += w0.y; e2 += w1.x; e3 += w1.y;
    }
    for (; i < end; i += 2) {
        int s = csc[i];
        short4 v = *(const short4*)(base + (size_t)s * DIM);
        float2 x0 = __half22float2(*(const __half2*)&v.x);
        float2 x1 = __half22float2(*(const __half2*)&v.z);
        a0 += x0.x; a1 += x0.y; a2 += x1.x; a3 += x1.y;
    }
    a0 += b0 + c0 + e0; a1 += b1 + c1 + e1;
    a2 += b2 + c2 + e2; a3 += b3 + c3 + e3;
    a0 += __shfl(a0, lane ^ 32);
    a1 += __shfl(a1, lane ^ 32);
    a2 += __shfl(a2, lane ^ 32);
    a3 += __shfl(a3, lane ^ 32);
    if (h == 0) {
        float c = cd[d];
        float4 bv = *(const float4*)&bias[l * 4];
        float4 o;
        o.x = fmaxf(fmaf(a0, c, bv.x), 0.f);
        o.y = fmaxf(fmaf(a1, c, bv.y), 0.f);
        o.z = fmaxf(fmaf(a2, c, bv.z), 0.f);
        o.w = fmaxf(fmaf(a3, c, bv.w), 0.f);
        *(float4*)&out[(size_t)d * DIM + l * 4] = o;
    }
}

// R[u][:] = tanh(h[users[u]] @ Ws1 + bs1) @ Ws2 + bs2
__global__ __launch_bounds__(256) void k_sr_head(const float* __restrict__ h,
                                                 const int* __restrict__ users,
                                                 const float* __restrict__ Ws1,
                                                 const float* __restrict__ bs1,
                                                 const float* __restrict__ Ws2,
                                                 const float* __restrict__ bs2,
                                                 float* __restrict__ R, int nu) {
    __shared__ float sW1[DIM * 64];
    __shared__ float sW2[64 * 64];
    __shared__ float sU[4][DIM];
    __shared__ float sT[4][64];
    for (int i = threadIdx.x * 4; i < DIM * 64; i += 256 * 4)
        *(float4*)&sW1[i] = *(const float4*)&Ws1[i];
    for (int i = threadIdx.x * 4; i < 64 * 64; i += 256 * 4)
        *(float4*)&sW2[i] = *(const float4*)&Ws2[i];
    int ul = threadIdx.x >> 6;
    int c = threadIdx.x & 63;
    for (int base = blockIdx.x * 4; base < nu; base += gridDim.x * 4) {
        int u = base + ul;
        __syncthreads();
        if (u < nu) {
            int node = users[u];
            *(float2*)&sU[ul][c * 2] = *(const float2*)&h[(size_t)node * DIM + c * 2];
        }
        __syncthreads();
        float t = 0.f;
        if (u < nu) {
            float acc = bs1[c];
#pragma unroll 8
            for (int k = 0; k < DIM; ++k) acc = fmaf(sU[ul][k], sW1[k * 64 + c], acc);
            t = tanhf(acc);
        }
        sT[ul][c] = t;
        __syncthreads();
        if (u < nu) {
            float acc = bs2[c];
#pragma unroll 8
            for (int k = 0; k < 64; ++k) acc = fmaf(sT[ul][k], sW2[k * 64 + c], acc);
            R[(size_t)u * 64 + c] = acc;
        }
    }
}

extern "C" void kernel_launch(void* const* d_in, const int* in_sizes, int n_in,
                              void* d_out, int out_size, void* d_ws, size_t ws_size,
                              hipStream_t stream) {
    const float* features = (const float*)d_in[0];
    const float* W0  = (const float*)d_in[1];
    const float* b0  = (const float*)d_in[2];
    const float* W1  = (const float*)d_in[3];
    const float* b1  = (const float*)d_in[4];
    const float* Ws1 = (const float*)d_in[5];
    const float* bs1 = (const float*)d_in[6];
    const float* Ws2 = (const float*)d_in[7];
    const float* bs2 = (const float*)d_in[8];
    const int* src   = (const int*)d_in[9];
    const int* dst   = (const int*)d_in[10];
    const int* users = (const int*)d_in[11];

    float* R = (float*)d_out;
    float* H = (float*)d_out + (size_t)NU * 64;

    char* ws = (char*)d_ws;
    __half* hsA  = (__half*)(ws + 0);                      // 12.8 MB
    unsigned int* histD = (unsigned int*)(ws + 0);         // 12.8 MB (256 x 50000B)
    unsigned int* histS = (unsigned int*)(ws + 12800000);  // 12.8 MB
    unsigned char* rel8 = (unsigned char*)(ws + 12800000); // 12.8 MB (overlays dead histS)
    unsigned short* csc = (unsigned short*)(ws + 25600000);//  3.2 MB (uint16 ids)
    int*   din   = (int*)  (ws + 28800000);
    float* cs    = (float*)(ws + 29000000);
    float* cd    = (float*)(ws + 29200000);
    int*   offs  = (int*)  (ws + 29400000);
    int*   partials = (int*)(ws + 29600000);

    k_hist<<<2 * NB, 1024, 0, stream>>>((const int4*)src, (const int4*)dst, histD, histS);
    k_reduce_norms<<<NRB, 256, 0, stream>>>(histD, histS, din, cs, cd, partials);
    k_scan3<<<NRB, 128, 0, stream>>>(din, partials, offs);
    k_blockbase<<<(NN + 255) / 256, 256, 0, stream>>>(histD, rel8);
    k_scatter2<<<NB, 1024, 0, stream>>>((const int4*)src, (const int4*)dst, offs, rel8, csc);

    // layer 1
    k_matmul_mfma<<<782, 256, 0, stream>>>(features, W0, cs, hsA, NN);
    k_aggregate<<<12500, 256, 0, stream>>>(hsA, csc, offs, din, cd, b0, H);

    // layer 2
    k_matmul_mfma<<<782, 256, 0, stream>>>(H, W1, cs, hsA, NN);
    k_aggregate<<<12500, 256, 0, stream>>>(hsA, csc, offs, din, cd, b1, H);

    // SR head
    k_sr_head<<<625, 256, 0, stream>>>(H, users, Ws1, bs1, Ws2, bs2, R, NU);
}